// Round 9
// baseline (379.273 us; speedup 1.0000x reference)
//
#include <hip/hip_runtime.h>

typedef __bf16 bf16;
typedef __bf16 bf16x4 __attribute__((ext_vector_type(4)));
typedef __bf16 bf16x8 __attribute__((ext_vector_type(8)));
typedef float f32x4 __attribute__((ext_vector_type(4)));
typedef float f32x16 __attribute__((ext_vector_type(16)));

constexpr int BATCH = 32;
constexpr int SEQ   = 1024;
constexpr int CDIM  = 768;
constexpr int ROWS  = BATCH * SEQ;   // 32768
constexpr int QKVC  = 3 * CDIM;      // 2304

// ---- workspace layout (bytes), ~273.3 MB total ----
constexpr size_t oWqT = 0;                                    // bf16 WqkvT [2304][768]
constexpr size_t oWpT = oWqT + (size_t)QKVC * CDIM * 2;       // bf16 WprojT [768][768]
constexpr size_t oQKV = oWpT + (size_t)CDIM * CDIM * 2;       // bf16 qkv [32768][2304]
constexpr size_t oS   = oQKV + (size_t)ROWS * QKVC * 2;       // bf16 S [32][1024][1024]
constexpr size_t oVT  = oS   + (size_t)BATCH * SEQ * SEQ * 2; // bf16 VT [32][768][1024]
constexpr size_t oInv = oVT  + (size_t)BATCH * CDIM * SEQ * 2;// f32 invsum [32768]
constexpr size_t oAO  = oQKV; // attn_out aliases qkv (q/k dead after QK^T)
constexpr size_t oXB  = oS;   // bf16(x) aliases S (dead before QK^T writes S)
constexpr size_t oPart= oWqT; // f32 partial[32768][4] aliases WqT (dead after qkv GEMM)

__device__ __forceinline__ void gld_lds16(const void* g, void* l) {
  __builtin_amdgcn_global_load_lds(
      (const __attribute__((address_space(1))) unsigned int*)g,
      (__attribute__((address_space(3))) unsigned int*)l,
      16, 0, 0);
}

// ---------- x fp32 -> bf16 ----------
__global__ __launch_bounds__(256) void f2b_kernel(const float* __restrict__ x,
                                                  bf16* __restrict__ y) {
  int i = blockIdx.x * blockDim.x + threadIdx.x;
  const float* p = x + (size_t)i * 8;
  float4 a = *(const float4*)p;
  float4 b = *(const float4*)(p + 4);
  bf16x8 o;
  o[0]=(bf16)a.x; o[1]=(bf16)a.y; o[2]=(bf16)a.z; o[3]=(bf16)a.w;
  o[4]=(bf16)b.x; o[5]=(bf16)b.y; o[6]=(bf16)b.z; o[7]=(bf16)b.w;
  *(bf16x8*)(y + (size_t)i * 8) = o;
}

// ---------- weight transpose+convert (tiled): T[n][k] = bf16(W[k][n]) ----------
__global__ __launch_bounds__(256) void wt_kernel(const float* __restrict__ W,
                                                 bf16* __restrict__ T, int N) {
  __shared__ float t[32][33];
  int k0 = blockIdx.x * 32, n0 = blockIdx.y * 32;
  int tx = threadIdx.x & 31, ty = threadIdx.x >> 5; // 32 x 8
  #pragma unroll
  for (int i = 0; i < 4; ++i)
    t[ty + i * 8][tx] = W[(size_t)(k0 + ty + i * 8) * N + n0 + tx];
  __syncthreads();
  #pragma unroll
  for (int i = 0; i < 4; ++i)
    T[(size_t)(n0 + ty + i * 8) * 768 + k0 + tx] = (bf16)t[tx][ty + i * 8];
}

// ---------- finish: inv[row] = 1 / sum_nt partial[row][nt] ----------
__global__ __launch_bounds__(256) void finish_kernel(const float* __restrict__ partial,
                                                     float* __restrict__ inv) {
  int i = blockIdx.x * 256 + threadIdx.x;
  float4 p = *(const float4*)(partial + (size_t)i * 4);
  inv[i] = 1.0f / (p.x + p.y + p.z + p.w);
}

// ============ 256x256 8-wave NT GEMM, round-8 schedule, 32x32x16 MFMA ============
// Same staging/wait/barrier skeleton as round 8 (invariant-derived, verified):
//   P1: rd a0,b0; stage B0(t+1); MMA(q00)   P2: rd a1; stage B1(t+1); MMA(q10)
//   midBAR (A region free)                  P3: rd b1; stage A0(t+2); MMA(q11)
//   P4: stage A1(t+2); MMA(q01)             top: vmcnt(4) [A(t+2) flies]; BAR
// MFMA shape 32x32x16 (2382 TF ceiling vs 2075; half the issue slots).
// Fragments: lane holds row/col lane&31, k=(lane>>5)*8+e -> 1 ds_read_b128 per
// MFMA at byte (s*32 + (lane>>5)*16) ^ swz. C/D: col=lane&31,
// row=(reg&3)+8*(reg>>2)+4*(lane>>5) [m74/m101-verified].
// T2 swizzle unchanged: read-row&7 == lane&7 for all fragment rows.

#define DSRD_A32(dst_, hf_) do {                                                 \
  _Pragma("unroll")                                                              \
  for (int mb_ = 0; mb_ < 2; ++mb_) {                                            \
    const int row_ = wm * 128 + (hf_) * 64 + mb_ * 32 + (lane & 31);             \
    const char* rb_ = (const char*)Acur + row_ * 128;                            \
    _Pragma("unroll")                                                            \
    for (int s_ = 0; s_ < 4; ++s_)                                               \
      dst_[mb_][s_] = *(const bf16x8*)(rb_ + ((s_ * 32 + khi) ^ swz));           \
  }                                                                              \
} while (0)

#define DSRD_B32(dst_, nb_) do {                                                 \
  const int row_ = wn * 64 + (nb_) * 32 + (lane & 31);                           \
  const char* rb_ = (const char*)Bcur + row_ * 128;                              \
  _Pragma("unroll")                                                              \
  for (int s_ = 0; s_ < 4; ++s_)                                                 \
    dst_[s_] = *(const bf16x8*)(rb_ + ((s_ * 32 + khi) ^ swz));                  \
} while (0)

#define STG_A(buf_, kt_, h_) do {                                                \
  gld_lds16(Ast + (size_t)((h_) * 128 +  0) * lda + (size_t)(kt_) * 64,          \
            &LDSB[(buf_)][((h_) * 2 + 0) * 4096 + wv * 512]);                    \
  gld_lds16(Ast + (size_t)((h_) * 128 + 64) * lda + (size_t)(kt_) * 64,          \
            &LDSB[(buf_)][((h_) * 2 + 1) * 4096 + wv * 512]);                    \
} while (0)

#define STG_B(buf_, kt_, h_) do {                                                \
  gld_lds16(Bst + (size_t)((h_) * 128 +  0) * ldb + (size_t)(kt_) * 64,          \
            &LDSB[2 + (buf_)][((h_) * 2 + 0) * 4096 + wv * 512]);                \
  gld_lds16(Bst + (size_t)((h_) * 128 + 64) * ldb + (size_t)(kt_) * 64,          \
            &LDSB[2 + (buf_)][((h_) * 2 + 1) * 4096 + wv * 512]);                \
} while (0)

#define MMA32(a_, b_, mo_, nb_) do {                                             \
  asm volatile("s_waitcnt lgkmcnt(0)" ::: "memory");                             \
  __builtin_amdgcn_sched_barrier(0);                                             \
  __builtin_amdgcn_s_setprio(1);                                                 \
  _Pragma("unroll")                                                              \
  for (int s_ = 0; s_ < 4; ++s_)                                                 \
    _Pragma("unroll")                                                            \
    for (int i_ = 0; i_ < 2; ++i_)                                               \
      acc[(mo_) + i_][nb_] =                                                     \
          __builtin_amdgcn_mfma_f32_32x32x16_bf16(a_[i_][s_], b_[s_],            \
              acc[(mo_) + i_][nb_], 0, 0, 0);                                    \
  __builtin_amdgcn_s_setprio(0);                                                 \
} while (0)

#define PIN() __builtin_amdgcn_sched_barrier(0)
#define BAR() __builtin_amdgcn_s_barrier()

template<bool OUT_BF16, bool HAS_BIAS, bool ROW_SCALE, bool FUSE_EXP, bool TR_V>
__global__ __launch_bounds__(512, 2) void gemm256(
    const bf16* __restrict__ Ap, const bf16* __restrict__ Bp, void* __restrict__ Cp,
    int K, int lda, int ldb, int ldc, int ntm, int ntn,
    long sA, long sB, long sC,
    float scale, const float* __restrict__ rowScale, long sRS,
    const float* __restrict__ bias, float* __restrict__ partial,
    bf16* __restrict__ vtout)
{
  __shared__ __align__(16) bf16 LDSB[4][256 * 64]; // [A0,A1,B0,B1], 128 KiB
  const int tid  = threadIdx.x;
  const int lane = tid & 63;
  const int wv   = tid >> 6;      // 0..7
  const int wm   = wv >> 2;       // 0..1  (128-row half)
  const int wn   = wv & 3;        // 0..3  (64-col strip)

  // XCD-chunked bijective swizzle (grid always a multiple of 8 here)
  const int total = (int)gridDim.x;
  const int chunk = total >> 3;
  const int bid   = (int)blockIdx.x;
  int sbid = (bid & 7) * chunk + (bid >> 3);
  const int pb = ntm * ntn;
  const int z  = sbid / pb;  sbid -= z * pb;
  const int mt = sbid / ntn;
  const int nt = sbid - mt * ntn;
  const int m0 = mt * 256, n0 = nt * 256;

  const bf16* A = Ap + (size_t)z * sA;
  const bf16* B = Bp + (size_t)z * sB;

  // staging map: row sr (0..63 per segment), chunk sc8; global chunk pre-swizzled
  const int sr  = tid >> 3;
  const int sc8 = tid & 7;
  const int gch = sc8 ^ (sr & 7);
  const bf16* Ast = A + (size_t)(m0 + sr) * lda + gch * 8;
  const bf16* Bst = B + (size_t)(n0 + sr) * ldb + gch * 8;

  const int swz = (lane & 7) << 4;
  const int khi = (lane >> 5) * 16;   // k-half byte offset for 32x32 fragments
  const int hi  = lane >> 5;
  const int col = lane & 31;

  f32x16 acc[4][2] = {};
  const int nkt = K >> 6;

  // prologue: tile0 (8 loads) then A(1) (4 loads, MUST be newest for vmcnt(4))
  STG_A(0, 0, 0); STG_A(0, 0, 1);
  STG_B(0, 0, 0); STG_B(0, 0, 1);
  if (nkt > 1) { STG_A(1, 1, 0); STG_A(1, 1, 1); }

  bf16x8 a0[2][4], a1[2][4], b0[4], b1[4];
  for (int t = 0; t < nkt; ++t) {
    const int cur = t & 1;
    const bf16* Acur = LDSB[cur];
    const bf16* Bcur = LDSB[2 + cur];
    const bool sb = (t + 1 < nkt);
    const bool sa = (t + 2 < nkt);
    // tile top: per-wave counted drain (tile t fully landed; A(t+2) may fly),
    // THEN publish barrier.
    if (sa) asm volatile("s_waitcnt vmcnt(4)" ::: "memory");
    else    asm volatile("s_waitcnt vmcnt(0)" ::: "memory");
    BAR(); PIN();
    // P1: quadrant (m-blocks 0-1, n-block 0); stage B0(t+1) into free buf cur^1
    DSRD_A32(a0, 0); DSRD_B32(b0, 0);
    PIN();
    if (sb) STG_B(cur ^ 1, t + 1, 0);
    MMA32(a0, b0, 0, 0);
    // P2: (m-blocks 2-3, n0) — reuse b0; stage B1(t+1)
    DSRD_A32(a1, 1);
    PIN();
    if (sb) STG_B(cur ^ 1, t + 1, 1);
    MMA32(a1, b0, 2, 0);
    BAR(); PIN();   // A(t) fully read by all waves -> A region of cur reusable
    // P3: (m-blocks 2-3, n1) — reuse a1; stage A0(t+2) in place
    DSRD_B32(b1, 1);
    PIN();
    if (sa) STG_A(cur, t + 2, 0);
    MMA32(a1, b1, 2, 1);
    // P4: (m-blocks 0-1, n1) — reuse a0,b1; stage A1(t+2)
    if (sa) STG_A(cur, t + 2, 1);
    PIN();
    MMA32(a0, b1, 0, 1);
  }

  // epilogue: 32x32 C/D layout col=lane&31, row=(reg&3)+8*(reg>>2)+4*hi
  if (TR_V && nt >= 6) {
    // V block: write transposed to VT via LDS (row-major qkv store skipped)
    bf16* tile = LDSB[0];   // 256 c-rows x 512 B, XOR-swizzled; uses all 128 KiB
    __syncthreads();
    #pragma unroll
    for (int mb = 0; mb < 4; ++mb) {
      #pragma unroll
      for (int nb = 0; nb < 2; ++nb) {
        const int lc = wn * 64 + nb * 32 + col;          // c within tile
        #pragma unroll
        for (int rg = 0; rg < 4; ++rg) {
          const int lm = wm * 128 + mb * 32 + rg * 8 + 4 * hi; // 4 consecutive m
          bf16x4 w;
          #pragma unroll
          for (int r = 0; r < 4; ++r) {
            float v = acc[mb][nb][rg * 4 + r] * scale;
            if (HAS_BIAS) v += bias[n0 + lc];
            w[r] = (bf16)v;
          }
          *(bf16x4*)((char*)tile + lc * 512 + ((lm * 2) ^ ((lc & 7) << 4))) = w;
        }
      }
    }
    __syncthreads();
    const int bz = m0 >> 10;          // batch index (256-row tile within one batch)
    const int mb2 = m0 & 1023;
    bf16* dst = vtout + ((size_t)bz * CDIM + (n0 - 2 * CDIM)) * SEQ + mb2;
    #pragma unroll
    for (int it = 0; it < 16; ++it) {
      const int c  = (tid >> 5) + it * 16;
      const int ch = tid & 31;
      bf16x8 vv = *(const bf16x8*)((const char*)tile + c * 512 + ((ch * 16) ^ ((c & 7) << 4)));
      *(bf16x8*)(dst + (size_t)c * SEQ + ch * 8) = vv;
    }
  } else if (FUSE_EXP) {
    float* sl = (float*)LDSB;  // [4 strips][256 rows], LDS free after K-loop
    __syncthreads();
    #pragma unroll
    for (int mb = 0; mb < 4; ++mb) {
      #pragma unroll
      for (int reg = 0; reg < 16; ++reg) {
        const int wrow = wm * 128 + mb * 32 + (reg & 3) + 8 * (reg >> 2) + 4 * hi;
        const int gm = m0 + wrow;
        float e0 = __expf(acc[mb][0][reg] * scale);
        float e1 = __expf(acc[mb][1][reg] * scale);
        ((bf16*)Cp)[(size_t)z * sC + (size_t)gm * ldc + (n0 + wn * 64 + col)]      = (bf16)e0;
        ((bf16*)Cp)[(size_t)z * sC + (size_t)gm * ldc + (n0 + wn * 64 + 32 + col)] = (bf16)e1;
        float s = e0 + e1;
        s += __shfl_xor(s, 1); s += __shfl_xor(s, 2); s += __shfl_xor(s, 4);
        s += __shfl_xor(s, 8); s += __shfl_xor(s, 16);
        if (col == 0) sl[wn * 256 + wrow] = s;
      }
    }
    __syncthreads();
    if (tid < 256) {
      float s = sl[tid] + sl[256 + tid] + sl[512 + tid] + sl[768 + tid];
      partial[((size_t)z * SEQ + m0 + tid) * 4 + nt] = s;
    }
  } else {
    #pragma unroll
    for (int mb = 0; mb < 4; ++mb) {
      #pragma unroll
      for (int nb = 0; nb < 2; ++nb) {
        const int gn = n0 + wn * 64 + nb * 32 + col;
        #pragma unroll
        for (int reg = 0; reg < 16; ++reg) {
          const int gm = m0 + wm * 128 + mb * 32 + (reg & 3) + 8 * (reg >> 2) + 4 * hi;
          float v = acc[mb][nb][reg] * scale;
          if (ROW_SCALE) v *= rowScale[(size_t)z * sRS + gm];
          if (HAS_BIAS)  v += bias[gn];
          if (OUT_BF16) ((bf16*)Cp)[(size_t)z * sC + (size_t)gm * ldc + gn] = (bf16)v;
          else          ((float*)Cp)[(size_t)z * sC + (size_t)gm * ldc + gn] = v;
        }
      }
    }
  }
}

extern "C" void kernel_launch(void* const* d_in, const int* in_sizes, int n_in,
                              void* d_out, int out_size, void* d_ws, size_t ws_size,
                              hipStream_t stream) {
  const float* x     = (const float*)d_in[0];
  const float* Wqkv  = (const float*)d_in[1];
  const float* bqkv  = (const float*)d_in[2];
  const float* Wproj = (const float*)d_in[3];
  const float* bproj = (const float*)d_in[4];
  float* out = (float*)d_out;
  char*  ws  = (char*)d_ws;

  bf16*  WqT = (bf16*)(ws + oWqT);
  bf16*  WpT = (bf16*)(ws + oWpT);
  bf16*  qkv = (bf16*)(ws + oQKV);
  bf16*  S   = (bf16*)(ws + oS);
  bf16*  VT  = (bf16*)(ws + oVT);
  float* inv = (float*)(ws + oInv);
  bf16*  AO  = (bf16*)(ws + oAO);
  bf16*  xb  = (bf16*)(ws + oXB);
  float* part= (float*)(ws + oPart);

  const float qk_scale = 1.0f / sqrtf((float)CDIM);

  // 1. conversions / transposes
  f2b_kernel<<<ROWS * CDIM / 8 / 256, 256, 0, stream>>>(x, xb);
  wt_kernel<<<dim3(768 / 32, QKVC / 32), 256, 0, stream>>>(Wqkv, WqT, QKVC);
  wt_kernel<<<dim3(768 / 32, CDIM / 32), 256, 0, stream>>>(Wproj, WpT, CDIM);

  // 2. qkv = xb @ WqT^T + b_qkv; V third written transposed to VT (TR_V)
  gemm256<true, true, false, false, true><<<(ROWS / 256) * (QKVC / 256), 512, 0, stream>>>(
      xb, WqT, qkv, CDIM, CDIM, CDIM, QKVC, ROWS / 256, QKVC / 256,
      0, 0, 0, 1.0f, nullptr, 0, bqkv, nullptr, VT);

  // 3. S = exp(q @ k^T * scale), fused row-partial sums (overwrites xb & WqT — both dead)
  gemm256<true, false, false, true, false><<<BATCH * (SEQ / 256) * (SEQ / 256), 512, 0, stream>>>(
      qkv, qkv + CDIM, S, CDIM, QKVC, QKVC, SEQ, SEQ / 256, SEQ / 256,
      (long)SEQ * QKVC, (long)SEQ * QKVC, (long)SEQ * SEQ, qk_scale, nullptr, 0, nullptr, part, nullptr);

  // 4. inv = 1/rowsum  (sums the 4 n-tile partials)
  finish_kernel<<<ROWS / 256, 256, 0, stream>>>(part, inv);

  // 5. attn_out = (expS @ VT^T) * inv[row]   [32 x 1024 x 768]
  gemm256<true, false, true, false, false><<<BATCH * (SEQ / 256) * (CDIM / 256), 512, 0, stream>>>(
      S, VT, AO, SEQ, SEQ, SEQ, CDIM, SEQ / 256, CDIM / 256,
      (long)SEQ * SEQ, (long)CDIM * SEQ, (long)SEQ * CDIM, 1.0f, inv, SEQ, nullptr, nullptr, nullptr);

  // 6. out = attn_out @ WpT^T + b_proj   [32768 x 768], fp32
  gemm256<false, true, false, false, false><<<(ROWS / 256) * (CDIM / 256), 512, 0, stream>>>(
      AO, WpT, out, CDIM, CDIM, CDIM, CDIM, ROWS / 256, CDIM / 256,
      0, 0, 0, 1.0f, nullptr, 0, bproj, nullptr, nullptr);
}

// Round 10
// 330.019 us; speedup vs baseline: 1.1492x; 1.1492x over previous
//
#include <hip/hip_runtime.h>

typedef __bf16 bf16;
typedef __bf16 bf16x4 __attribute__((ext_vector_type(4)));
typedef __bf16 bf16x8 __attribute__((ext_vector_type(8)));
typedef float f32x4 __attribute__((ext_vector_type(4)));

constexpr int BATCH = 32;
constexpr int SEQ   = 1024;
constexpr int CDIM  = 768;
constexpr int ROWS  = BATCH * SEQ;   // 32768
constexpr int QKVC  = 3 * CDIM;      // 2304

// ---- workspace layout (bytes), ~273.3 MB total ----
constexpr size_t oWqT = 0;                                    // bf16 WqkvT [2304][768]
constexpr size_t oWpT = oWqT + (size_t)QKVC * CDIM * 2;       // bf16 WprojT [768][768]
constexpr size_t oQKV = oWpT + (size_t)CDIM * CDIM * 2;       // bf16 qkv [32768][2304]
constexpr size_t oS   = oQKV + (size_t)ROWS * QKVC * 2;       // bf16 S [32][1024][1024]
constexpr size_t oVT  = oS   + (size_t)BATCH * SEQ * SEQ * 2; // bf16 VT [32][768][1024]
constexpr size_t oInv = oVT  + (size_t)BATCH * CDIM * SEQ * 2;// f32 invsum [32768]
constexpr size_t oAO  = oQKV; // attn_out aliases qkv (q/k dead after QK^T)
constexpr size_t oXB  = oS;   // bf16(x) aliases S (dead before QK^T writes S)
constexpr size_t oPart= oWqT; // f32 partial[32768][8] (1 MB) aliases WqT (dead after qkv)

__device__ __forceinline__ void gld_lds16(const void* g, void* l) {
  __builtin_amdgcn_global_load_lds(
      (const __attribute__((address_space(1))) unsigned int*)g,
      (__attribute__((address_space(3))) unsigned int*)l,
      16, 0, 0);
}

// ---------- x fp32 -> bf16 ----------
__global__ __launch_bounds__(256) void f2b_kernel(const float* __restrict__ x,
                                                  bf16* __restrict__ y) {
  int i = blockIdx.x * blockDim.x + threadIdx.x;
  const float* p = x + (size_t)i * 8;
  float4 a = *(const float4*)p;
  float4 b = *(const float4*)(p + 4);
  bf16x8 o;
  o[0]=(bf16)a.x; o[1]=(bf16)a.y; o[2]=(bf16)a.z; o[3]=(bf16)a.w;
  o[4]=(bf16)b.x; o[5]=(bf16)b.y; o[6]=(bf16)b.z; o[7]=(bf16)b.w;
  *(bf16x8*)(y + (size_t)i * 8) = o;
}

// ---------- weight transpose+convert (tiled): T[n][k] = bf16(W[k][n]) ----------
__global__ __launch_bounds__(256) void wt_kernel(const float* __restrict__ W,
                                                 bf16* __restrict__ T, int N) {
  __shared__ float t[32][33];
  int k0 = blockIdx.x * 32, n0 = blockIdx.y * 32;
  int tx = threadIdx.x & 31, ty = threadIdx.x >> 5; // 32 x 8
  #pragma unroll
  for (int i = 0; i < 4; ++i)
    t[ty + i * 8][tx] = W[(size_t)(k0 + ty + i * 8) * N + n0 + tx];
  __syncthreads();
  #pragma unroll
  for (int i = 0; i < 4; ++i)
    T[(size_t)(n0 + ty + i * 8) * 768 + k0 + tx] = (bf16)t[tx][ty + i * 8];
}

// ---------- finish: inv[row] = 1 / sum_{nt<8} partial[row][nt] ----------
__global__ __launch_bounds__(256) void finish_kernel(const float* __restrict__ partial,
                                                     float* __restrict__ inv) {
  int i = blockIdx.x * 256 + threadIdx.x;
  float4 p0 = *(const float4*)(partial + (size_t)i * 8);
  float4 p1 = *(const float4*)(partial + (size_t)i * 8 + 4);
  inv[i] = 1.0f / (p0.x + p0.y + p0.z + p0.w + p1.x + p1.y + p1.z + p1.w);
}

// ============ 128x128 4-wave NT GEMM — m97 structure (912-TF class) =============
// C[z][m][n] = scale*rowScale[z][m]*sum_k A[z][m][k]*B[z][n][k] + bias[n]
// BK=64, single 32 KiB LDS buffer (As+Bs), 2 barriers/K-tile (__syncthreads
// drains vmcnt+lgkm before s_barrier — the m97 semantics). No explicit
// pipelining: 3 blocks/CU (launch_bounds cap) provide cross-block overlap
// (m114 wave-level overlap; m99/m100: explicit dbuf adds nothing here).
// T2 swizzle (rule 21, measured 0-conflict in rounds 4-8): linear LDS dest,
// inverse-swizzled GLOBAL chunk (tid&7)^(sr&7), read byte kb^((row&7)<<4).
// FUSE_EXP (QK^T): store bf16(exp(acc*scale)), row partials -> partial[row][8].
// TR_V (qkv): n-tiles >=12 (V cols) write VT transposed via 32 KiB LDS tile.

template<bool OUT_BF16, bool HAS_BIAS, bool ROW_SCALE, bool FUSE_EXP, bool TR_V>
__global__ __launch_bounds__(256, 3) void gemm128(
    const bf16* __restrict__ Ap, const bf16* __restrict__ Bp, void* __restrict__ Cp,
    int K, int lda, int ldb, int ldc, int ntm, int ntn,
    long sA, long sB, long sC,
    float scale, const float* __restrict__ rowScale, long sRS,
    const float* __restrict__ bias, float* __restrict__ partial,
    bf16* __restrict__ vtout)
{
  __shared__ __align__(16) bf16 LDS[128 * 128];   // 32 KiB: As | Bs
  bf16* As = LDS;
  bf16* Bs = LDS + 128 * 64;
  const int tid  = threadIdx.x;
  const int lane = tid & 63;
  const int wv   = tid >> 6;      // 0..3
  const int wm   = wv >> 1;       // 0..1 (64-row half)
  const int wn   = wv & 1;        // 0..1 (64-col half)

  // XCD-chunked bijective swizzle (grid always a multiple of 8 here)
  const int total = (int)gridDim.x;
  const int chunk = total >> 3;
  const int bid   = (int)blockIdx.x;
  int sbid = (bid & 7) * chunk + (bid >> 3);
  const int pb = ntm * ntn;
  const int z  = sbid / pb;  sbid -= z * pb;
  const int mt = sbid / ntn;
  const int nt = sbid - mt * ntn;
  const int m0 = mt * 128, n0 = nt * 128;

  const bf16* A = Ap + (size_t)z * sA;
  const bf16* B = Bp + (size_t)z * sB;

  // staging map: row sr (0..31 per quarter), chunk gch pre-swizzled (rule 21)
  const int sr  = tid >> 3;
  const int gch = (tid & 7) ^ (sr & 7);
  const bf16* Ast = A + (size_t)(m0 + sr) * lda + gch * 8;
  const bf16* Bst = B + (size_t)(n0 + sr) * ldb + gch * 8;

  const int lr  = lane & 15;
  const int hi  = lane >> 4;
  const int swz = (lane & 7) << 4;
  const int kb0 = hi * 16;

  f32x4 acc[4][4] = {};

  for (int kt = 0; kt < K; kt += 64) {
    #pragma unroll
    for (int it = 0; it < 4; ++it) {
      gld_lds16(Ast + (size_t)(it * 32) * lda + kt, As + it * 2048 + wv * 512);
      gld_lds16(Bst + (size_t)(it * 32) * ldb + kt, Bs + it * 2048 + wv * 512);
    }
    __syncthreads();   // drains vmcnt+lgkm then barrier (m97 semantics)
    #pragma unroll
    for (int ks = 0; ks < 2; ++ks) {
      bf16x8 af[4], bfr[4];
      #pragma unroll
      for (int i = 0; i < 4; ++i) {
        const int rm = wm * 64 + i * 16 + lr;
        af[i]  = *(const bf16x8*)((const char*)As + rm * 128 + ((ks * 64 + kb0) ^ swz));
        const int rn = wn * 64 + i * 16 + lr;
        bfr[i] = *(const bf16x8*)((const char*)Bs + rn * 128 + ((ks * 64 + kb0) ^ swz));
      }
      #pragma unroll
      for (int i = 0; i < 4; ++i)
        #pragma unroll
        for (int j = 0; j < 4; ++j)
          acc[i][j] = __builtin_amdgcn_mfma_f32_16x16x32_bf16(af[i], bfr[j], acc[i][j], 0, 0, 0);
    }
    __syncthreads();   // protect LDS before next-tile stage / epilogue reuse
  }

  // epilogue: C/D layout col=lane&15, row=(lane>>4)*4+reg (m89-verified)
  if (TR_V && nt >= 12) {
    // V block: write transposed to VT via LDS tile [128 c][256 B], XOR-swizzled
    bf16* tile = LDS;
    #pragma unroll
    for (int i = 0; i < 4; ++i) {
      #pragma unroll
      for (int j = 0; j < 4; ++j) {
        const int lc = wn * 64 + j * 16 + lr;       // c within tile
        const int lm = wm * 64 + i * 16 + hi * 4;   // 4 consecutive m
        bf16x4 w;
        #pragma unroll
        for (int r = 0; r < 4; ++r) {
          float v = acc[i][j][r] * scale;
          if (HAS_BIAS) v += bias[n0 + lc];
          w[r] = (bf16)v;
        }
        *(bf16x4*)((char*)tile + lc * 256 + ((lm * 2) ^ ((lc & 7) << 4))) = w;
      }
    }
    __syncthreads();
    const int bz = m0 >> 10;
    const int mb = m0 & 1023;
    bf16* dst = vtout + ((size_t)bz * CDIM + (n0 - 2 * CDIM)) * SEQ + mb;
    #pragma unroll
    for (int it = 0; it < 8; ++it) {
      const int cid = it * 256 + tid;
      const int c   = cid >> 4;
      const int ch  = cid & 15;
      bf16x8 vv = *(const bf16x8*)((const char*)tile + c * 256 + ((ch * 16) ^ ((c & 7) << 4)));
      *(bf16x8*)(dst + (size_t)c * SEQ + ch * 8) = vv;
    }
  } else if (FUSE_EXP) {
    float rs[4][4];
    #pragma unroll
    for (int i = 0; i < 4; ++i)
      #pragma unroll
      for (int r = 0; r < 4; ++r) rs[i][r] = 0.f;
    #pragma unroll
    for (int i = 0; i < 4; ++i)
      #pragma unroll
      for (int j = 0; j < 4; ++j)
        #pragma unroll
        for (int r = 0; r < 4; ++r) {
          const int gm = m0 + wm * 64 + i * 16 + hi * 4 + r;
          const int gn = n0 + wn * 64 + j * 16 + lr;
          float e = __expf(acc[i][j][r] * scale);
          ((bf16*)Cp)[(size_t)z * sC + (size_t)gm * ldc + gn] = (bf16)e;
          rs[i][r] += e;
        }
    float* sl = (float*)LDS;   // [2 wn-strips][128 rows], LDS free after K-loop
    #pragma unroll
    for (int i = 0; i < 4; ++i)
      #pragma unroll
      for (int r = 0; r < 4; ++r) {
        float s = rs[i][r];
        s += __shfl_xor(s, 1); s += __shfl_xor(s, 2);
        s += __shfl_xor(s, 4); s += __shfl_xor(s, 8);
        if (lr == 0)
          sl[wn * 128 + wm * 64 + i * 16 + hi * 4 + r] = s;
      }
    __syncthreads();
    if (tid < 128)
      partial[((size_t)z * SEQ + m0 + tid) * 8 + nt] = sl[tid] + sl[128 + tid];
  } else {
    #pragma unroll
    for (int i = 0; i < 4; ++i) {
      #pragma unroll
      for (int j = 0; j < 4; ++j) {
        #pragma unroll
        for (int r = 0; r < 4; ++r) {
          const int gm = m0 + wm * 64 + i * 16 + hi * 4 + r;
          const int gn = n0 + wn * 64 + j * 16 + lr;
          float v = acc[i][j][r] * scale;
          if (ROW_SCALE) v *= rowScale[(size_t)z * sRS + gm];
          if (HAS_BIAS)  v += bias[gn];
          if (OUT_BF16) ((bf16*)Cp)[(size_t)z * sC + (size_t)gm * ldc + gn] = (bf16)v;
          else          ((float*)Cp)[(size_t)z * sC + (size_t)gm * ldc + gn] = v;
        }
      }
    }
  }
}

extern "C" void kernel_launch(void* const* d_in, const int* in_sizes, int n_in,
                              void* d_out, int out_size, void* d_ws, size_t ws_size,
                              hipStream_t stream) {
  const float* x     = (const float*)d_in[0];
  const float* Wqkv  = (const float*)d_in[1];
  const float* bqkv  = (const float*)d_in[2];
  const float* Wproj = (const float*)d_in[3];
  const float* bproj = (const float*)d_in[4];
  float* out = (float*)d_out;
  char*  ws  = (char*)d_ws;

  bf16*  WqT = (bf16*)(ws + oWqT);
  bf16*  WpT = (bf16*)(ws + oWpT);
  bf16*  qkv = (bf16*)(ws + oQKV);
  bf16*  S   = (bf16*)(ws + oS);
  bf16*  VT  = (bf16*)(ws + oVT);
  float* inv = (float*)(ws + oInv);
  bf16*  AO  = (bf16*)(ws + oAO);
  bf16*  xb  = (bf16*)(ws + oXB);
  float* part= (float*)(ws + oPart);

  const float qk_scale = 1.0f / sqrtf((float)CDIM);

  // 1. conversions / transposes
  f2b_kernel<<<ROWS * CDIM / 8 / 256, 256, 0, stream>>>(x, xb);
  wt_kernel<<<dim3(768 / 32, QKVC / 32), 256, 0, stream>>>(Wqkv, WqT, QKVC);
  wt_kernel<<<dim3(768 / 32, CDIM / 32), 256, 0, stream>>>(Wproj, WpT, CDIM);

  // 2. qkv = xb @ WqT^T + b_qkv; V third (nt>=12) written transposed to VT
  gemm128<true, true, false, false, true><<<(ROWS / 128) * (QKVC / 128), 256, 0, stream>>>(
      xb, WqT, qkv, CDIM, CDIM, CDIM, QKVC, ROWS / 128, QKVC / 128,
      0, 0, 0, 1.0f, nullptr, 0, bqkv, nullptr, VT);

  // 3. S = exp(q @ k^T * scale), fused row-partial sums (overwrites xb & WqT)
  gemm128<true, false, false, true, false><<<BATCH * (SEQ / 128) * (SEQ / 128), 256, 0, stream>>>(
      qkv, qkv + CDIM, S, CDIM, QKVC, QKVC, SEQ, SEQ / 128, SEQ / 128,
      (long)SEQ * QKVC, (long)SEQ * QKVC, (long)SEQ * SEQ, qk_scale, nullptr, 0, nullptr, part, nullptr);

  // 4. inv = 1/rowsum  (sums the 8 n-tile partials)
  finish_kernel<<<ROWS / 256, 256, 0, stream>>>(part, inv);

  // 5. attn_out = (expS @ VT^T) * inv[row]   [32 x 1024 x 768]
  gemm128<true, false, true, false, false><<<BATCH * (SEQ / 128) * (CDIM / 128), 256, 0, stream>>>(
      S, VT, AO, SEQ, SEQ, SEQ, CDIM, SEQ / 128, CDIM / 128,
      (long)SEQ * SEQ, (long)CDIM * SEQ, (long)SEQ * CDIM, 1.0f, inv, SEQ, nullptr, nullptr, nullptr);

  // 6. out = attn_out @ WpT^T + b_proj   [32768 x 768], fp32
  gemm128<false, true, false, false, false><<<(ROWS / 128) * (CDIM / 128), 256, 0, stream>>>(
      AO, WpT, out, CDIM, CDIM, CDIM, CDIM, ROWS / 128, CDIM / 128,
      0, 0, 0, 1.0f, nullptr, 0, bproj, nullptr, nullptr);
}